// Round 1
// 3350.471 us; speedup vs baseline: 1.4139x; 1.4139x over previous
//
#include <hip/hip_runtime.h>
#include <hip/hip_bf16.h>
#include <math.h>

#define LSEQ 2048
#define DMODEL 768
#define DINNER 1536
#define DSTATE 16
#define DTRANK 48
#define NLAYER 4
#define XDBL_W 80   /* DTRANK + 2*DSTATE */
#define CH 64       /* scan chunks */
#define SLEN 32     /* steps per chunk, CH*SLEN == LSEQ */

typedef __attribute__((ext_vector_type(4))) float f32x4;
typedef __attribute__((ext_vector_type(8))) short short8;
typedef __attribute__((ext_vector_type(8))) __bf16 bf16x8;
typedef __attribute__((ext_vector_type(4))) unsigned short us4;

__device__ inline float softplus_f(float x) {
    return fmaxf(x, 0.f) + log1pf(expf(-fabsf(x)));
}
__device__ inline float silu_f(float x) {
    return x / (1.f + expf(-x));
}

/* bf16 round-to-nearest-even via bit ops (no exotic-type dependence) */
__device__ inline unsigned short f2bf(float f) {
    unsigned int u = __float_as_uint(f);
    unsigned int r = (u + 0x7fffu + ((u >> 16) & 1u)) >> 16;
    return (unsigned short)r;
}
__device__ inline float bf2f(unsigned short b) {
    return __uint_as_float((unsigned int)b << 16);
}

__device__ inline f32x4 mfma_bf16_16x16x32(short8 a, short8 b, f32x4 c) {
    return __builtin_amdgcn_mfma_f32_16x16x32_bf16(
        __builtin_bit_cast(bf16x8, a), __builtin_bit_cast(bf16x8, b), c, 0, 0, 0);
}

#define GLDS16(gp, lp) __builtin_amdgcn_global_load_lds( \
    (const __attribute__((address_space(1))) void*)(gp), \
    (__attribute__((address_space(3))) void*)(lp), 16, 0, 0)

/* ---------------- embedding gather ---------------- */
__global__ __launch_bounds__(256) void embed_kernel(
    const int* __restrict__ ids, const float* __restrict__ emb,
    float* __restrict__ x)
{
    int l = blockIdx.x;
    int id = ids[l];
    const float* src = emb + (size_t)id * DMODEL;
    float* dst = x + (size_t)l * DMODEL;
    for (int j = threadIdx.x; j < DMODEL; j += 256) dst[j] = src[j];
}

/* ---------------- rmsnorm (block per row) ---------------- */
__global__ __launch_bounds__(256) void rmsnorm_kernel(
    const float* __restrict__ x, const float* __restrict__ w,
    float* __restrict__ o)
{
    int row = blockIdx.x;
    const float* xr = x + (size_t)row * DMODEL;
    float ss = 0.f;
    for (int j = threadIdx.x; j < DMODEL; j += 256) { float v = xr[j]; ss += v * v; }
    __shared__ float red[256];
    red[threadIdx.x] = ss;
    __syncthreads();
    for (int s = 128; s > 0; s >>= 1) {
        if (threadIdx.x < s) red[threadIdx.x] += red[threadIdx.x + s];
        __syncthreads();
    }
    float scale = rsqrtf(red[0] / DMODEL + 1e-5f);
    for (int j = threadIdx.x; j < DMODEL; j += 256)
        o[(size_t)row * DMODEL + j] = xr[j] * scale * w[j];
}

/* ---------------- generic fp32 GEMM: C[M,N] = A[M,K] * B[N,K]^T ----------------
 * mode 0: store
 * mode 1: softplus(acc + bias[n])
 * mode 2: C += acc  (residual accumulate)
 * LDS padded +4 floats: store pattern was 4-way bank conflict (row stride 64
 * words == 0 mod 32 banks); stride 68 -> lk*4 mod 32 spread, float4 reads stay
 * 16B-aligned (272 B row stride). */
#define BM 64
#define BN 64
#define BK 16
__global__ __launch_bounds__(256) void gemm_nt(
    const float* __restrict__ A, const float* __restrict__ B,
    float* __restrict__ C, int M, int N, int K,
    int lda, int ldb, int ldc, int mode, const float* __restrict__ bias)
{
    __shared__ float As[BK][BM + 4];
    __shared__ float Bs[BK][BN + 4];
    int tid = threadIdx.x;
    int tx = tid & 15;
    int ty = tid >> 4;
    int row0 = blockIdx.y * BM;
    int col0 = blockIdx.x * BN;

    int lm = tid >> 2;          /* 0..63 */
    int lk = (tid & 3) * 4;     /* 0,4,8,12 */

    float acc[4][4];
#pragma unroll
    for (int i = 0; i < 4; ++i)
#pragma unroll
        for (int j = 0; j < 4; ++j) acc[i][j] = 0.f;

    for (int k0 = 0; k0 < K; k0 += BK) {
        {
            int gm = row0 + lm;
            float4 v = make_float4(0.f, 0.f, 0.f, 0.f);
            if (gm < M) v = *(const float4*)(A + (size_t)gm * lda + k0 + lk);
            As[lk + 0][lm] = v.x; As[lk + 1][lm] = v.y;
            As[lk + 2][lm] = v.z; As[lk + 3][lm] = v.w;
            int gn = col0 + lm;
            float4 w = make_float4(0.f, 0.f, 0.f, 0.f);
            if (gn < N) w = *(const float4*)(B + (size_t)gn * ldb + k0 + lk);
            Bs[lk + 0][lm] = w.x; Bs[lk + 1][lm] = w.y;
            Bs[lk + 2][lm] = w.z; Bs[lk + 3][lm] = w.w;
        }
        __syncthreads();
#pragma unroll
        for (int k = 0; k < BK; ++k) {
            float4 a = *(const float4*)(&As[k][ty * 4]);
            float4 b = *(const float4*)(&Bs[k][tx * 4]);
            float av[4] = { a.x, a.y, a.z, a.w };
            float bv[4] = { b.x, b.y, b.z, b.w };
#pragma unroll
            for (int i = 0; i < 4; ++i)
#pragma unroll
                for (int j = 0; j < 4; ++j) acc[i][j] += av[i] * bv[j];
        }
        __syncthreads();
    }

#pragma unroll
    for (int i = 0; i < 4; ++i) {
        int m = row0 + ty * 4 + i;
        if (m >= M) continue;
#pragma unroll
        for (int j = 0; j < 4; ++j) {
            int n = col0 + tx * 4 + j;
            if (n >= N) continue;
            float v = acc[i][j];
            if (mode == 1) v = softplus_f(v + bias[n]);
            else if (mode == 2) v += C[(size_t)m * ldc + n];
            C[(size_t)m * ldc + n] = v;
        }
    }
}

/* ---------------- split f32 -> (bf16 hi, bf16 lo) ----------------
 * lo = bf16(x - f32(hi)); pad region (idx >= srcElems) written as zeros. */
__global__ __launch_bounds__(256) void split_bf16_kernel(
    const float* __restrict__ src, unsigned short* __restrict__ hi,
    unsigned short* __restrict__ lo, long long srcElems, long long totElems)
{
    long long idx = ((long long)blockIdx.x * 256 + threadIdx.x) * 4;
    if (idx >= totElems) return;
    float4 v = make_float4(0.f, 0.f, 0.f, 0.f);
    if (idx < srcElems) v = *(const float4*)(src + idx);
    unsigned short h0 = f2bf(v.x), h1 = f2bf(v.y), h2 = f2bf(v.z), h3 = f2bf(v.w);
    us4 hv = { h0, h1, h2, h3 };
    us4 lv = { f2bf(v.x - bf2f(h0)), f2bf(v.y - bf2f(h1)),
               f2bf(v.z - bf2f(h2)), f2bf(v.w - bf2f(h3)) };
    *(us4*)(hi + idx) = hv;
    *(us4*)(lo + idx) = lv;
}

/* ---------------- logits GEMM: bf16 MFMA, 3-term split ----------------
 * C[M=2048,N] = (Ah+Al)(Bh+Bl)^T approx = Ah*Bh^T + Al*Bh^T + Ah*Bl^T
 * computed as one GEMM over virtual K = 3*768, base pointers selected per
 * 768-block. m97 structure: 128x128 tile, 4 waves (2x2, each 64x64),
 * mfma_f32_16x16x32_bf16, global_load_lds width-16 staging, linear LDS.
 * C/D lane map (m89-verified): row=(lane>>4)*4+i, col=lane&15. */
__global__ __launch_bounds__(256) void gemm_logits_mfma(
    const unsigned short* __restrict__ Ah, const unsigned short* __restrict__ Al,
    const unsigned short* __restrict__ Bh, const unsigned short* __restrict__ Bl,
    float* __restrict__ C, int N)
{
    __shared__ unsigned short As[128 * 32];  /* [row][k], 64 B rows */
    __shared__ unsigned short Bs[128 * 32];
    int tid = threadIdx.x;
    int lane = tid & 63;
    int wid = tid >> 6;
    int wrow = wid >> 1, wcol = wid & 1;
    int brow0 = blockIdx.x * 128;   /* x = row tile: consecutive blocks share B panel */
    int bcol0 = blockIdx.y * 128;

    f32x4 acc[4][4];
#pragma unroll
    for (int m = 0; m < 4; ++m)
#pragma unroll
        for (int n = 0; n < 4; ++n) acc[m][n] = (f32x4){ 0.f, 0.f, 0.f, 0.f };

    /* staging geometry: wave w stages tile rows [w*32, w*32+32) via 2 issues
     * of 16 rows; lane covers row += lane>>2, kbytes (lane&3)*16.
     * LDS dest is wave-uniform base + lane*16 (HW rule) == linear row-major. */
    int arow = brow0 + wid * 32 + (lane >> 2);
    int bcol = bcol0 + wid * 32 + (lane >> 2);
    int kb = (lane & 3) * 8;                   /* bf16 elems within the 16B chunk */
    char* lbaseA = (char*)As + wid * 2048;     /* wave-uniform */
    char* lbaseB = (char*)Bs + wid * 2048;

    for (int vb = 0; vb < 3; ++vb) {
        const unsigned short* Ab = (vb == 1) ? Al : Ah;
        const unsigned short* Bb = (vb == 2) ? Bl : Bh;
        for (int k0 = 0; k0 < DMODEL; k0 += 32) {
#pragma unroll
            for (int j = 0; j < 2; ++j) {
                GLDS16(Ab + (size_t)(arow + j * 16) * DMODEL + k0 + kb, lbaseA + j * 1024);
                GLDS16(Bb + (size_t)(bcol + j * 16) * DMODEL + k0 + kb, lbaseB + j * 1024);
            }
            __syncthreads();   /* drains vmcnt before LDS reads */
            short8 af[4], bfr[4];
#pragma unroll
            for (int m = 0; m < 4; ++m)
                af[m] = *(const short8*)(As + ((wrow * 64 + m * 16 + (lane & 15)) * 32 + (lane >> 4) * 8));
#pragma unroll
            for (int n = 0; n < 4; ++n)
                bfr[n] = *(const short8*)(Bs + ((wcol * 64 + n * 16 + (lane & 15)) * 32 + (lane >> 4) * 8));
#pragma unroll
            for (int m = 0; m < 4; ++m)
#pragma unroll
                for (int n = 0; n < 4; ++n)
                    acc[m][n] = mfma_bf16_16x16x32(af[m], bfr[n], acc[m][n]);
            __syncthreads();   /* protect LDS before next stage */
        }
    }

    int r0 = brow0 + wrow * 64 + (lane >> 4) * 4;
    int c0 = bcol0 + wcol * 64 + (lane & 15);
#pragma unroll
    for (int m = 0; m < 4; ++m)
#pragma unroll
        for (int n = 0; n < 4; ++n) {
            int col = c0 + n * 16;
            if (col >= N) continue;
#pragma unroll
            for (int i = 0; i < 4; ++i)
                C[(size_t)(r0 + m * 16 + i) * N + col] = acc[m][n][i];
        }
}

/* ---------------- depthwise causal conv (k=4) + silu ---------------- */
__global__ __launch_bounds__(256) void conv_silu_kernel(
    const float* __restrict__ xr, const float* __restrict__ cw,
    const float* __restrict__ cb, float* __restrict__ u)
{
    int idx = blockIdx.x * 256 + threadIdx.x;
    if (idx >= LSEQ * DINNER) return;
    int l = idx / DINNER;
    int d = idx - l * DINNER;
    float s = cb[d];
#pragma unroll
    for (int t = 0; t < 4; ++t) {
        int ll = l - 3 + t;
        if (ll >= 0) s += xr[(size_t)ll * (2 * DINNER) + d] * cw[d * 4 + t];
    }
    u[idx] = silu_f(s);
}

/* ---------------- A = -exp(A_log) ---------------- */
__global__ __launch_bounds__(256) void neg_exp_kernel(
    const float* __restrict__ a, float* __restrict__ o, int n)
{
    int i = blockIdx.x * 256 + threadIdx.x;
    if (i < n) o[i] = -expf(a[i]);
}

/* ---------------- chunked selective scan ---------------- */
__global__ __launch_bounds__(256) void scan_phase1(
    const float* __restrict__ delta, const float* __restrict__ u,
    const float* __restrict__ xdbl, const float* __restrict__ Aneg,
    float* __restrict__ cA, float* __restrict__ cB)
{
    int tid = threadIdx.x;
    int n = tid & 15;
    int d = blockIdx.x * 16 + (tid >> 4);
    int c = blockIdx.y;
    float Av = Aneg[d * DSTATE + n];
    float h = 0.f, ap = 1.f;
    int l = c * SLEN;
    for (int s = 0; s < SLEN; ++s, ++l) {
        float dt = delta[(size_t)l * DINNER + d];
        float uv = u[(size_t)l * DINNER + d];
        float Bv = xdbl[l * XDBL_W + DTRANK + n];
        float a = expf(dt * Av);
        h = a * h + dt * Bv * uv;
        ap *= a;
    }
    size_t off = ((size_t)c * DINNER + d) * DSTATE + n;
    cA[off] = ap;
    cB[off] = h;
}

__global__ __launch_bounds__(256) void scan_phase2(
    const float* __restrict__ cA, const float* __restrict__ cB,
    float* __restrict__ hs)
{
    int idx = blockIdx.x * 256 + threadIdx.x; /* over DINNER*DSTATE */
    float h = 0.f;
    for (int c = 0; c < CH; ++c) {
        size_t off = (size_t)c * DINNER * DSTATE + idx;
        hs[off] = h;
        h = cA[off] * h + cB[off];
    }
}

__global__ __launch_bounds__(256) void scan_phase3(
    const float* __restrict__ delta, const float* __restrict__ u,
    const float* __restrict__ xdbl, const float* __restrict__ Aneg,
    const float* __restrict__ hs, const float* __restrict__ Dp,
    const float* __restrict__ xr, float* __restrict__ y)
{
    int tid = threadIdx.x;
    int n = tid & 15;
    int d = blockIdx.x * 16 + (tid >> 4);
    int c = blockIdx.y;
    float Av = Aneg[d * DSTATE + n];
    float Dv = Dp[d];
    float h = hs[((size_t)c * DINNER + d) * DSTATE + n];
    int l = c * SLEN;
    for (int s = 0; s < SLEN; ++s, ++l) {
        float dt = delta[(size_t)l * DINNER + d];
        float uv = u[(size_t)l * DINNER + d];
        float Bv = xdbl[l * XDBL_W + DTRANK + n];
        float Cv = xdbl[l * XDBL_W + DTRANK + DSTATE + n];
        float a = expf(dt * Av);
        h = a * h + dt * Bv * uv;
        float p = h * Cv;
        p += __shfl_down(p, 8, 16);
        p += __shfl_down(p, 4, 16);
        p += __shfl_down(p, 2, 16);
        p += __shfl_down(p, 1, 16);
        if (n == 0) {
            float r = xr[(size_t)l * (2 * DINNER) + DINNER + d];
            y[(size_t)l * DINNER + d] = (p + uv * Dv) * silu_f(r);
        }
    }
}

extern "C" void kernel_launch(void* const* d_in, const int* in_sizes, int n_in,
                              void* d_out, int out_size, void* d_ws, size_t ws_size,
                              hipStream_t stream)
{
    const int*   ids   = (const int*)d_in[0];
    const float* emb   = (const float*)d_in[1];
    const float* in_w  = (const float*)d_in[2];
    const float* cw    = (const float*)d_in[3];
    const float* cb    = (const float*)d_in[4];
    const float* xpw   = (const float*)d_in[5];
    const float* dtw   = (const float*)d_in[6];
    const float* dtb   = (const float*)d_in[7];
    const float* A_log = (const float*)d_in[8];
    const float* Dp    = (const float*)d_in[9];
    const float* ow    = (const float*)d_in[10];
    const float* nw    = (const float*)d_in[11];
    const float* nfw   = (const float*)d_in[12];
    float* out = (float*)d_out;

    const int VOCAB = in_sizes[1] / DMODEL; /* 50264 */
    const int Npad = ((VOCAB + 127) / 128) * 128; /* 50304 */

    float* ws = (float*)d_ws;
    size_t o = 0;
    float* x     = ws + o; o += (size_t)LSEQ * DMODEL;
    float* h     = ws + o; o += (size_t)LSEQ * DMODEL;
    float* xr    = ws + o; o += (size_t)LSEQ * 2 * DINNER;
    float* u     = ws + o; o += (size_t)LSEQ * DINNER;
    float* xdbl  = ws + o; o += (size_t)LSEQ * XDBL_W;
    float* delta = ws + o; o += (size_t)LSEQ * DINNER;
    float* Aneg  = ws + o; o += (size_t)DINNER * DSTATE;
    float* cA    = ws + o; o += (size_t)CH * DINNER * DSTATE;
    float* cB    = ws + o; o += (size_t)CH * DINNER * DSTATE;
    float* hsb   = ws + o; o += (size_t)CH * DINNER * DSTATE;
    float* y     = ws + o; o += (size_t)LSEQ * DINNER;
    /* bf16 split buffers (2 B/elem; counted in float units) */
    unsigned short* Ahi = (unsigned short*)(ws + o); o += (size_t)LSEQ * DMODEL / 2;
    unsigned short* Alo = (unsigned short*)(ws + o); o += (size_t)LSEQ * DMODEL / 2;
    unsigned short* Bhi = (unsigned short*)(ws + o); o += (size_t)Npad * DMODEL / 2;
    unsigned short* Blo = (unsigned short*)(ws + o); o += (size_t)Npad * DMODEL / 2;

    /* emb -> bf16 hi/lo split (one-shot, padded rows zeroed) */
    {
        long long srcElems = (long long)VOCAB * DMODEL;
        long long totElems = (long long)Npad * DMODEL;
        int nb = (int)((totElems / 4 + 255) / 256);
        split_bf16_kernel<<<nb, 256, 0, stream>>>(emb, Bhi, Blo, srcElems, totElems);
    }

    embed_kernel<<<LSEQ, 256, 0, stream>>>(ids, emb, x);

    for (int i = 0; i < NLAYER; ++i) {
        rmsnorm_kernel<<<LSEQ, 256, 0, stream>>>(x, nw + (size_t)i * DMODEL, h);

        /* x_and_res = h @ in_w^T : (2048,3072) */
        gemm_nt<<<dim3(2 * DINNER / BN, LSEQ / BM), 256, 0, stream>>>(
            h, in_w + (size_t)i * 2 * DINNER * DMODEL, xr,
            LSEQ, 2 * DINNER, DMODEL, DMODEL, DMODEL, 2 * DINNER, 0, nullptr);

        conv_silu_kernel<<<(LSEQ * DINNER + 255) / 256, 256, 0, stream>>>(
            xr, cw + (size_t)i * DINNER * 4, cb + (size_t)i * DINNER, u);

        /* x_dbl = u @ xpw^T : (2048,80) */
        gemm_nt<<<dim3((XDBL_W + BN - 1) / BN, LSEQ / BM), 256, 0, stream>>>(
            u, xpw + (size_t)i * XDBL_W * DINNER, xdbl,
            LSEQ, XDBL_W, DINNER, DINNER, DINNER, XDBL_W, 0, nullptr);

        /* delta = softplus(x_dbl[:, :48] @ dtw^T + dtb) : (2048,1536) */
        gemm_nt<<<dim3(DINNER / BN, LSEQ / BM), 256, 0, stream>>>(
            xdbl, dtw + (size_t)i * DINNER * DTRANK, delta,
            LSEQ, DINNER, DTRANK, XDBL_W, DTRANK, DINNER, 1,
            dtb + (size_t)i * DINNER);

        neg_exp_kernel<<<(DINNER * DSTATE + 255) / 256, 256, 0, stream>>>(
            A_log + (size_t)i * DINNER * DSTATE, Aneg, DINNER * DSTATE);

        scan_phase1<<<dim3(DINNER / 16, CH), 256, 0, stream>>>(
            delta, u, xdbl, Aneg, cA, cB);
        scan_phase2<<<DINNER * DSTATE / 256, 256, 0, stream>>>(cA, cB, hsb);
        scan_phase3<<<dim3(DINNER / 16, CH), 256, 0, stream>>>(
            delta, u, xdbl, Aneg, hsb, Dp + (size_t)i * DINNER, xr, y);

        /* x += y @ ow^T : (2048,768) */
        gemm_nt<<<dim3(DMODEL / BN, LSEQ / BM), 256, 0, stream>>>(
            y, ow + (size_t)i * DMODEL * DINNER, x,
            LSEQ, DMODEL, DINNER, DINNER, DINNER, DMODEL, 2, nullptr);
    }

    rmsnorm_kernel<<<LSEQ, 256, 0, stream>>>(x, nfw, h);

    /* h -> bf16 hi/lo split */
    {
        long long aElems = (long long)LSEQ * DMODEL;
        int nb = (int)((aElems / 4 + 255) / 256);
        split_bf16_kernel<<<nb, 256, 0, stream>>>(h, Ahi, Alo, aElems, aElems);
    }

    /* logits = h @ emb^T : (2048, VOCAB) via 3-term split-bf16 MFMA */
    gemm_logits_mfma<<<dim3(LSEQ / 128, Npad / 128), 256, 0, stream>>>(
        Ahi, Alo, Bhi, Blo, out, VOCAB);
}